// Round 11
// baseline (75.551 us; speedup 1.0000x reference)
//
#include <hip/hip_runtime.h>
#include <math.h>

namespace {
constexpr int kB = 16;
constexpr int kL = 240000;
constexpr int kD = 9;
constexpr float kInvSamp = 1.0f / 24000.0f;
constexpr int kChunk = 1024;
constexpr int kT = 4;              // samples per thread
constexpr int kThreads = 256;      // kChunk / kT
constexpr int kNChunks = 235;      // ceil(240000/1024); last chunk 384 samp
constexpr int kN4Full = kChunk * kD / 4;  // 2304 float4 of noise per chunk
constexpr float kSineAmp = 0.1f;
constexpr float kNoiseStd = 0.003f;
constexpr float kNoiseUnv = (float)(0.1 / 3.0);
}  // namespace

// ---------------- Pass A: per-chunk sum of rq = f0/SR -> agg[b*235+c]
__global__ __launch_bounds__(kThreads) void sine_pass_a(
    const float* __restrict__ f0, double* __restrict__ agg) {
  const int c = blockIdx.x, b = blockIdx.y, tid = threadIdx.x;
  const int l0 = c * kChunk + tid * kT;
  float s = 0.0f;
  if (l0 < kL) {
    const float4 a = *reinterpret_cast<const float4*>(f0 + (size_t)b * kL + l0);
    s = (a.x + a.y) + (a.z + a.w);
  }
  double v = (double)s * (double)kInvSamp;
#pragma unroll
  for (int ofs = 1; ofs < 64; ofs <<= 1) v += __shfl_xor(v, ofs, 64);
  __shared__ double wt[4];
  const int wid = tid >> 6;
  if ((tid & 63) == 0) wt[wid] = v;
  __syncthreads();
  if (tid == 0) agg[(size_t)b * kNChunks + c] = wt[0] + wt[1] + wt[2] + wt[3];
}

// ---------------- Emit: coalesced LDS-staged noise + shuffle scan + emit
__global__ __launch_bounds__(kThreads) void sine_emit(
    const float* __restrict__ f0, const float* __restrict__ rand_ini,
    const float* __restrict__ noise, const float* __restrict__ w,
    const double* __restrict__ agg, float* __restrict__ out) {
  __shared__ float4 nlds[kN4Full];  // 36,864 B
  __shared__ double rtot[4], wtot[4];
  const int c = blockIdx.x, b = blockIdx.y, tid = threadIdx.x;
  const int lane = tid & 63, wid = tid >> 6;
  const int l0 = c * kChunk + tid * kT;
  const bool active = l0 < kL;

  // ---- f0: one coalesced float4 per thread
  float rq[kT];
  float tsum = 0.0f;
  if (active) {
    const float4 a = *reinterpret_cast<const float4*>(f0 + (size_t)b * kL + l0);
    rq[0] = a.x * kInvSamp; rq[1] = a.y * kInvSamp;
    rq[2] = a.z * kInvSamp; rq[3] = a.w * kInvSamp;
    tsum = rq[0] + rq[1] + rq[2] + rq[3];
  } else {
#pragma unroll
    for (int j = 0; j < kT; ++j) rq[j] = 0.0f;
  }

  // ---- predecessor aggregate (issued before the noise stream)
  double pv = (tid < c) ? agg[(size_t)b * kNChunks + tid] : 0.0;

  // ---- noise: 9 wave-contiguous float4 loads (1 KB/instr coalescing)
  const int n4avail = (c == kNChunks - 1) ? ((kL - c * kChunk) * kD / 4)
                                          : kN4Full;  // tail: 864
  const float4* n4 = reinterpret_cast<const float4*>(
      noise + ((size_t)b * kL + (size_t)c * kChunk) * kD);
  float4 st[9];
#pragma unroll
  for (int k = 0; k < 9; ++k) {
    const int idx = k * kThreads + tid;
    if (idx < n4avail) st[k] = n4[idx];
  }

  // ---- wave-level reduce (pred aggs) + wave-level scan (tsum)
#pragma unroll
  for (int ofs = 1; ofs < 64; ofs <<= 1) pv += __shfl_xor(pv, ofs, 64);

  double incl = (double)tsum;
#pragma unroll
  for (int ofs = 1; ofs < 64; ofs <<= 1) {
    const double u = __shfl_up(incl, ofs, 64);
    if (lane >= ofs) incl += u;
  }

  if (lane == 0) rtot[wid] = pv;
  if (lane == 63) wtot[wid] = incl;

  // ---- stage noise into LDS (redistribution for per-thread reads)
#pragma unroll
  for (int k = 0; k < 9; ++k) {
    const int idx = k * kThreads + tid;
    if (idx < n4avail) nlds[idx] = st[k];
  }
  __syncthreads();  // one barrier covers scan partials + noise staging

  if (!active) return;

  double base = rtot[0] + rtot[1] + rtot[2] + rtot[3];  // pred-chunk sum
#pragma unroll
  for (int k = 0; k < 4; ++k)
    if (k < wid) base += wtot[k];  // preceding-wave totals
  const double cbase = base + incl - (double)tsum;  // exclusive prefix

  float basef[kD], wv[kD];
#pragma unroll
  for (int d = 0; d < kD; ++d) {
    const double ph = (double)(d + 1) * cbase + (double)rand_ini[b * kD + d];
    basef[d] = (float)(ph - floor(ph));
    wv[d] = w[d];
  }

  // ---- read own 144 B slice (float4-aligned: 144 = 9*16)
  float nz[kT * kD];
#pragma unroll
  for (int i = 0; i < 9; ++i) {
    const float4 x = nlds[tid * 9 + i];
    nz[4 * i + 0] = x.x; nz[4 * i + 1] = x.y;
    nz[4 * i + 2] = x.z; nz[4 * i + 3] = x.w;
  }

  float ob[kT];
  float pref = 0.0f;
#pragma unroll
  for (int j = 0; j < kT; ++j) {
    pref += rq[j];  // inclusive local prefix
    const float f = rq[j];
    const float au = (f > 0.0f) ? kSineAmp : 0.0f;
    const float namp = (f > 0.0f) ? kNoiseStd : kNoiseUnv;
    float dots = 0.0f, dotn = 0.0f;
#pragma unroll
    for (int d = 0; d < kD; ++d) {
      const float pf = __builtin_amdgcn_fractf(basef[d] + (float)(d + 1) * pref);
      const float sv = __builtin_amdgcn_sinf(pf);  // sin(2*pi*frac)
      dots = fmaf(wv[d], sv, dots);
      dotn = fmaf(wv[d], nz[j * kD + d], dotn);
    }
    const float x = au * dots + namp * dotn;
    const float e = __expf(2.0f * x);
    ob[j] = 1.0f - 2.0f * __builtin_amdgcn_rcpf(e + 1.0f);  // tanh(x)
  }

  *reinterpret_cast<float4*>(out + (size_t)b * kL + l0) =
      make_float4(ob[0], ob[1], ob[2], ob[3]);
}

extern "C" void kernel_launch(void* const* d_in, const int* in_sizes, int n_in,
                              void* d_out, int out_size, void* d_ws,
                              size_t ws_size, hipStream_t stream) {
  const float* f0 = (const float*)d_in[0];
  const float* rand_ini = (const float*)d_in[1];
  const float* noise = (const float*)d_in[2];
  const float* w = (const float*)d_in[3];
  float* out = (float*)d_out;
  double* agg = (double*)d_ws;  // kB * kNChunks doubles = 30,080 B

  const dim3 grid(kNChunks, kB), block(kThreads);
  sine_pass_a<<<grid, block, 0, stream>>>(f0, agg);
  sine_emit<<<grid, block, 0, stream>>>(f0, rand_ini, noise, w, agg, out);
}

// Round 12
// 40.358 us; speedup vs baseline: 1.8720x; 1.8720x over previous
//
#include <hip/hip_runtime.h>
#include <math.h>

namespace {
constexpr int kB = 16;
constexpr int kL = 240000;
constexpr int kD = 9;
constexpr float kInvSamp = 1.0f / 24000.0f;
constexpr int kChunk = 1024;
constexpr int kT = 4;              // samples per thread
constexpr int kThreads = 256;      // kChunk / kT
constexpr int kNChunks = 235;      // ceil(240000/1024); last chunk 384 samp
constexpr int kN4Full = kChunk * kD / 4;  // 2304 float4 of noise per chunk
constexpr float kSineAmp = 0.1f;
constexpr float kNoiseStd = 0.003f;
constexpr float kNoiseUnv = (float)(0.1 / 3.0);
}  // namespace

// ---------------- Pass A: per-chunk sum of rq = f0/SR -> agg[b*235+c]
__global__ __launch_bounds__(kThreads) void sine_pass_a(
    const float* __restrict__ f0, double* __restrict__ agg) {
  const int c = blockIdx.x, b = blockIdx.y, tid = threadIdx.x;
  const int l0 = c * kChunk + tid * kT;
  float s = 0.0f;
  if (l0 < kL) {
    const float4 a = *reinterpret_cast<const float4*>(f0 + (size_t)b * kL + l0);
    s = (a.x + a.y) + (a.z + a.w);
  }
  double v = (double)s * (double)kInvSamp;
#pragma unroll
  for (int ofs = 1; ofs < 64; ofs <<= 1) v += __shfl_xor(v, ofs, 64);
  __shared__ double wt[4];
  const int wid = tid >> 6;
  if ((tid & 63) == 0) wt[wid] = v;
  __syncthreads();
  if (tid == 0) agg[(size_t)b * kNChunks + c] = wt[0] + wt[1] + wt[2] + wt[3];
}

// ---------------- Emit: coalesced LDS-staged noise + shuffle scan + emit
// __launch_bounds__(256, 4): LDS (37.4 KB) caps us at 4 blocks/CU = 4
// waves/EU anyway; asking for exactly that lets the allocator use ~128
// VGPRs -- prevents the R11 scratch spill (VGPR=52, 138 MB spill traffic).
__global__ __launch_bounds__(kThreads, 4) void sine_emit(
    const float* __restrict__ f0, const float* __restrict__ rand_ini,
    const float* __restrict__ noise, const float* __restrict__ w,
    const double* __restrict__ agg, float* __restrict__ out) {
  __shared__ float4 nlds[kN4Full];  // 36,864 B
  __shared__ double rtot[4], wtot[4];
  const int c = blockIdx.x, b = blockIdx.y, tid = threadIdx.x;
  const int lane = tid & 63, wid = tid >> 6;
  const int l0 = c * kChunk + tid * kT;
  const bool active = l0 < kL;

  // ---- f0: one coalesced float4 per thread
  float rq[kT];
  float tsum = 0.0f;
  if (active) {
    const float4 a = *reinterpret_cast<const float4*>(f0 + (size_t)b * kL + l0);
    rq[0] = a.x * kInvSamp; rq[1] = a.y * kInvSamp;
    rq[2] = a.z * kInvSamp; rq[3] = a.w * kInvSamp;
    tsum = rq[0] + rq[1] + rq[2] + rq[3];
  } else {
#pragma unroll
    for (int j = 0; j < kT; ++j) rq[j] = 0.0f;
  }

  // ---- predecessor aggregate (issued before the noise stream)
  double pv = (tid < c) ? agg[(size_t)b * kNChunks + tid] : 0.0;

  // ---- noise: 9 wave-contiguous float4 loads -> LDS, fused copy
  // (compiler pipelines the window; no long-lived staging array)
  const int n4avail = (c == kNChunks - 1) ? ((kL - c * kChunk) * kD / 4)
                                          : kN4Full;  // tail: 864
  const float4* n4 = reinterpret_cast<const float4*>(
      noise + ((size_t)b * kL + (size_t)c * kChunk) * kD);
#pragma unroll
  for (int k = 0; k < 9; ++k) {
    const int idx = k * kThreads + tid;
    if (idx < n4avail) nlds[idx] = n4[idx];
  }

  // ---- wave-level reduce (pred aggs) + wave-level scan (tsum)
#pragma unroll
  for (int ofs = 1; ofs < 64; ofs <<= 1) pv += __shfl_xor(pv, ofs, 64);

  double incl = (double)tsum;
#pragma unroll
  for (int ofs = 1; ofs < 64; ofs <<= 1) {
    const double u = __shfl_up(incl, ofs, 64);
    if (lane >= ofs) incl += u;
  }

  if (lane == 0) rtot[wid] = pv;
  if (lane == 63) wtot[wid] = incl;
  __syncthreads();  // one barrier: scan partials + noise staging visible

  if (!active) return;

  double base = rtot[0] + rtot[1] + rtot[2] + rtot[3];  // pred-chunk sum
#pragma unroll
  for (int k = 0; k < 4; ++k)
    if (k < wid) base += wtot[k];  // preceding-wave totals
  const double cbase = base + incl - (double)tsum;  // exclusive prefix

  float basef[kD], wv[kD];
#pragma unroll
  for (int d = 0; d < kD; ++d) {
    const double ph = (double)(d + 1) * cbase + (double)rand_ini[b * kD + d];
    basef[d] = (float)(ph - floor(ph));
    wv[d] = w[d];
  }

  // ---- read own 144 B slice (9 x ds_read_b128)
  float nz[kT * kD];
#pragma unroll
  for (int i = 0; i < 9; ++i) {
    const float4 x = nlds[tid * 9 + i];
    nz[4 * i + 0] = x.x; nz[4 * i + 1] = x.y;
    nz[4 * i + 2] = x.z; nz[4 * i + 3] = x.w;
  }

  float ob[kT];
  float pref = 0.0f;
#pragma unroll
  for (int j = 0; j < kT; ++j) {
    pref += rq[j];  // inclusive local prefix
    const float f = rq[j];
    const float au = (f > 0.0f) ? kSineAmp : 0.0f;
    const float namp = (f > 0.0f) ? kNoiseStd : kNoiseUnv;
    float dots = 0.0f, dotn = 0.0f;
#pragma unroll
    for (int d = 0; d < kD; ++d) {
      const float pf = __builtin_amdgcn_fractf(basef[d] + (float)(d + 1) * pref);
      const float sv = __builtin_amdgcn_sinf(pf);  // sin(2*pi*frac)
      dots = fmaf(wv[d], sv, dots);
      dotn = fmaf(wv[d], nz[j * kD + d], dotn);
    }
    const float x = au * dots + namp * dotn;
    const float e = __expf(2.0f * x);
    ob[j] = 1.0f - 2.0f * __builtin_amdgcn_rcpf(e + 1.0f);  // tanh(x)
  }

  *reinterpret_cast<float4*>(out + (size_t)b * kL + l0) =
      make_float4(ob[0], ob[1], ob[2], ob[3]);
}

extern "C" void kernel_launch(void* const* d_in, const int* in_sizes, int n_in,
                              void* d_out, int out_size, void* d_ws,
                              size_t ws_size, hipStream_t stream) {
  const float* f0 = (const float*)d_in[0];
  const float* rand_ini = (const float*)d_in[1];
  const float* noise = (const float*)d_in[2];
  const float* w = (const float*)d_in[3];
  float* out = (float*)d_out;
  double* agg = (double*)d_ws;  // kB * kNChunks doubles = 30,080 B

  const dim3 grid(kNChunks, kB), block(kThreads);
  sine_pass_a<<<grid, block, 0, stream>>>(f0, agg);
  sine_emit<<<grid, block, 0, stream>>>(f0, rand_ini, noise, w, agg, out);
}

// Round 13
// 34.024 us; speedup vs baseline: 2.2205x; 1.1862x over previous
//
#include <hip/hip_runtime.h>
#include <math.h>

namespace {
constexpr int kB = 16;
constexpr int kL = 240000;
constexpr int kD = 9;
constexpr float kInvSamp = 1.0f / 24000.0f;
constexpr int kChunk = 1024;
constexpr int kT = 4;              // samples per thread
constexpr int kThreads = 256;      // kChunk / kT
constexpr int kNChunks = 235;      // ceil(240000/1024); last chunk 384 samp
constexpr float kSineAmp = 0.1f;
constexpr float kNoiseStd = 0.003f;
constexpr float kNoiseUnv = (float)(0.1 / 3.0);
}  // namespace

// ---------------- Pass A: per-chunk sum of rq = f0/SR -> agg[b*235+c]
__global__ __launch_bounds__(kThreads) void sine_pass_a(
    const float* __restrict__ f0, double* __restrict__ agg) {
  const int c = blockIdx.x, b = blockIdx.y, tid = threadIdx.x;
  const int l0 = c * kChunk + tid * kT;
  float s = 0.0f;
  if (l0 < kL) {
    const float4 a = *reinterpret_cast<const float4*>(f0 + (size_t)b * kL + l0);
    s = (a.x + a.y) + (a.z + a.w);
  }
  double v = (double)s * (double)kInvSamp;
#pragma unroll
  for (int ofs = 1; ofs < 64; ofs <<= 1) v += __shfl_xor(v, ofs, 64);
  __shared__ double wt[4];
  const int wid = tid >> 6;
  if ((tid & 63) == 0) wt[wid] = v;
  __syncthreads();
  if (tid == 0) agg[(size_t)b * kNChunks + c] = wt[0] + wt[1] + wt[2] + wt[3];
}

// ---------------- Emit: R10 structure at kT=4 (small-T tail granularity).
// __launch_bounds__(256,5): cap ~102 VGPR -- above the ~90 estimate so no
// R11-style scratch spill, below the 128 cliff; 5 blocks/CU resident.
__global__ __launch_bounds__(kThreads, 5) void sine_emit(
    const float* __restrict__ f0, const float* __restrict__ rand_ini,
    const float* __restrict__ noise, const float* __restrict__ w,
    const double* __restrict__ agg, float* __restrict__ out) {
  const int c = blockIdx.x, b = blockIdx.y, tid = threadIdx.x;
  const int lane = tid & 63, wid = tid >> 6;
  const int l0 = c * kChunk + tid * kT;
  const bool active = l0 < kL;

  // ---- f0: one coalesced float4 per thread
  float rq[kT];
  float tsum = 0.0f;
  if (active) {
    const float4 a = *reinterpret_cast<const float4*>(f0 + (size_t)b * kL + l0);
    rq[0] = a.x * kInvSamp; rq[1] = a.y * kInvSamp;
    rq[2] = a.z * kInvSamp; rq[3] = a.w * kInvSamp;
    tsum = rq[0] + rq[1] + rq[2] + rq[3];
  } else {
#pragma unroll
    for (int j = 0; j < kT; ++j) rq[j] = 0.0f;
  }

  // ---- predecessor aggregates: <=234 pred chunks, 2 lanes-chunks/thread
  double pv = 0.0;
  {
    const double* ab = agg + (size_t)b * kNChunks;
    if (tid < c) pv += ab[tid];
    if (tid + kThreads < c) pv += ab[tid + kThreads];
  }

  // ---- noise: 9 float4 loads, 144 B/thread strided (direct, no LDS)
  float nz[kT * kD];
  if (active) {
    const float4* n4 =
        reinterpret_cast<const float4*>(noise + ((size_t)b * kL + l0) * kD);
#pragma unroll
    for (int i = 0; i < 9; ++i) {
      const float4 x = n4[i];
      nz[4 * i + 0] = x.x; nz[4 * i + 1] = x.y;
      nz[4 * i + 2] = x.z; nz[4 * i + 3] = x.w;
    }
  }

  // ---- wave-level reduce (pred aggs) + wave-level scan (tsum), 1 barrier
#pragma unroll
  for (int ofs = 1; ofs < 64; ofs <<= 1) pv += __shfl_xor(pv, ofs, 64);

  double incl = (double)tsum;
#pragma unroll
  for (int ofs = 1; ofs < 64; ofs <<= 1) {
    const double u = __shfl_up(incl, ofs, 64);
    if (lane >= ofs) incl += u;
  }

  __shared__ double rtot[4], wtot[4];
  if (lane == 0) rtot[wid] = pv;
  if (lane == 63) wtot[wid] = incl;
  __syncthreads();

  if (!active) return;

  double base = rtot[0] + rtot[1] + rtot[2] + rtot[3];  // pred-chunk sum
#pragma unroll
  for (int k = 0; k < 4; ++k)
    if (k < wid) base += wtot[k];  // preceding-wave totals
  const double cbase = base + incl - (double)tsum;  // exclusive prefix

  float basef[kD], wv[kD];
#pragma unroll
  for (int d = 0; d < kD; ++d) {
    const double ph = (double)(d + 1) * cbase + (double)rand_ini[b * kD + d];
    basef[d] = (float)(ph - floor(ph));
    wv[d] = w[d];
  }

  float ob[kT];
  float pref = 0.0f;
#pragma unroll
  for (int j = 0; j < kT; ++j) {
    pref += rq[j];  // inclusive local prefix
    const float f = rq[j];
    const float au = (f > 0.0f) ? kSineAmp : 0.0f;
    const float namp = (f > 0.0f) ? kNoiseStd : kNoiseUnv;
    float dots = 0.0f, dotn = 0.0f;
#pragma unroll
    for (int d = 0; d < kD; ++d) {
      const float pf = __builtin_amdgcn_fractf(basef[d] + (float)(d + 1) * pref);
      const float sv = __builtin_amdgcn_sinf(pf);  // sin(2*pi*frac)
      dots = fmaf(wv[d], sv, dots);
      dotn = fmaf(wv[d], nz[j * kD + d], dotn);
    }
    const float x = au * dots + namp * dotn;
    const float e = __expf(2.0f * x);
    ob[j] = 1.0f - 2.0f * __builtin_amdgcn_rcpf(e + 1.0f);  // tanh(x)
  }

  *reinterpret_cast<float4*>(out + (size_t)b * kL + l0) =
      make_float4(ob[0], ob[1], ob[2], ob[3]);
}

extern "C" void kernel_launch(void* const* d_in, const int* in_sizes, int n_in,
                              void* d_out, int out_size, void* d_ws,
                              size_t ws_size, hipStream_t stream) {
  const float* f0 = (const float*)d_in[0];
  const float* rand_ini = (const float*)d_in[1];
  const float* noise = (const float*)d_in[2];
  const float* w = (const float*)d_in[3];
  float* out = (float*)d_out;
  double* agg = (double*)d_ws;  // kB * kNChunks doubles = 30,080 B

  const dim3 grid(kNChunks, kB), block(kThreads);
  sine_pass_a<<<grid, block, 0, stream>>>(f0, agg);
  sine_emit<<<grid, block, 0, stream>>>(f0, rand_ini, noise, w, agg, out);
}